// Round 8
// baseline (215.854 us; speedup 1.0000x reference)
//
#include <hip/hip_runtime.h>
#include <math.h>

// Problem constants (match reference)
#define B_    4
#define T_    2048
#define D_    1024
#define F_    4096
#define R_    (B_*T_)      // 8192 rows (b,t)
#define SEG_  64           // segments per time-chain
#define L_    (T_/SEG_)    // 32 steps per segment
#define DECAYF 0.9f
#define OMDF   0.1f        // 1 - decay
// Flag threshold below 0.5: the k4 fallback re-tests at exactly 0.5 in fp32,
// so flags only need NO FALSE NEGATIVES. fp8(x8-scaled) GEMM error is
// ~1e-3 RMS (6-sigma ~7e-3); margin 0.05 is ~7x worst plausible error.
#define FLAG_THRESH 0.45f

typedef __attribute__((ext_vector_type(4)))  int   i32x4;
typedef __attribute__((ext_vector_type(8)))  int   i32x8;
typedef __attribute__((ext_vector_type(16))) float f32x16;

// pack 4 floats into 4 fp8 e4m3 bytes (byte0 = first arg)
__device__ __forceinline__ int pk_fp8x4(float x, float y, float z, float w) {
    int p = 0;
    p = __builtin_amdgcn_cvt_pk_fp8_f32(x, y, p, false);  // bytes 0,1
    p = __builtin_amdgcn_cvt_pk_fp8_f32(z, w, p, true);   // bytes 2,3
    return p;
}

__device__ __forceinline__ void gload_lds16(const void* g, void* l) {
    __builtin_amdgcn_global_load_lds(
        (const __attribute__((address_space(1))) unsigned int*)g,
        (__attribute__((address_space(3))) unsigned int*)l, 16, 0, 0);
}

// ---------------------------------------------------------------------------
// KA: fused prologue. Grid-partitioned roles:
//   blocks [0, 4096):       W1 fp32 -> fp8 e4m3, values x8 (scale 2^-3 in MFMA)
//   blocks [4096, 4352):    per-segment EMA end-state (seg_sum)
//   blocks [4352, 4384):    zero the 8192 per-row spike flags
#define KA_W1_BLOCKS  4096
#define KA_SEG_BLOCKS 256
#define KA_FLAG_BLOCKS 32

__global__ __launch_bounds__(256)
void kA_prologue(const float* __restrict__ spikes,
                 const float* __restrict__ W1,
                 unsigned char* __restrict__ w_f8,
                 float* __restrict__ seg_sum,
                 unsigned int* __restrict__ flags) {
    const int bid = blockIdx.x;
    const int tid = threadIdx.x;
    if (bid < KA_W1_BLOCKS) {
        int i = bid * 256 + tid;                  // float4 index
        float4 v = ((const float4*)W1)[i];
        ((int*)w_f8)[i] = pk_fp8x4(8.f*v.x, 8.f*v.y, 8.f*v.z, 8.f*v.w);
    } else if (bid < KA_W1_BLOCKS + KA_SEG_BLOCKS) {
        int t = (bid - KA_W1_BLOCKS) * 256 + tid; // B_*SEG_*D_/4 threads
        int dg = t & (D_ / 4 - 1);
        int s = (t >> 8) & (SEG_ - 1);
        int b = t >> 14;
        const float4* sp4 = (const float4*)spikes;
        const int base = (b * T_ + s * L_) * (D_ / 4) + dg;
        float4 e = {0.f, 0.f, 0.f, 0.f};
#pragma unroll 8
        for (int k = 0; k < L_; ++k) {
            float4 x = sp4[base + k * (D_ / 4)];
            e.x = DECAYF * e.x + OMDF * x.x;
            e.y = DECAYF * e.y + OMDF * x.y;
            e.z = DECAYF * e.z + OMDF * x.z;
            e.w = DECAYF * e.w + OMDF * x.w;
        }
        ((float4*)seg_sum)[(b * SEG_ + s) * (D_ / 4) + dg] = e;
    } else {
        int i = (bid - KA_W1_BLOCKS - KA_SEG_BLOCKS) * 256 + tid;
        if (i < R_) flags[i] = 0u;
    }
}

// ---------------------------------------------------------------------------
// KB: weighted Kogge-Stone scan over the 64 segments of each (b,d) chain,
// one chain per 64-lane wave (lane = segment). start_state[s] = scan[s-1].
__global__ __launch_bounds__(256)
void kB_seg_scan(const float* __restrict__ seg_sum,
                 float* __restrict__ start_state) {
    int g = blockIdx.x * 256 + threadIdx.x;   // B_*D_*64 threads
    int s = g & 63;                           // segment = lane
    int c = g >> 6;                           // chain id: 0..B_*D_-1
    int d = c & (D_ - 1);
    int b = c >> 10;
    int idx = (b * SEG_ + s) * D_ + d;
    float v = seg_sum[idx];
    float wp = 0.0343368382f;                 // 0.9^32 (per-segment decay)
#pragma unroll
    for (int off = 1; off < SEG_; off <<= 1) {
        float u = __shfl_up(v, off, 64);
        if (s >= off) v += wp * u;
        wp *= wp;                             // w^1, w^2, w^4, ...
    }
    float pv = __shfl_up(v, 1, 64);
    start_state[idx] = (s == 0) ? 0.f : pv;
}

// ---------------------------------------------------------------------------
// KC: recompute segment-local EMA seeded with start_state; emit fp8 (x8).
__global__ __launch_bounds__(256)
void kC_ema_fp8(const float* __restrict__ spikes,
                const float* __restrict__ start_state,
                unsigned char* __restrict__ a_f8) {
    int t = blockIdx.x * 256 + threadIdx.x;            // B_*SEG_*D_/4 threads
    int dg = t & (D_ / 4 - 1);
    int s = (t >> 8) & (SEG_ - 1);
    int b = t >> 14;
    const float4* sp4 = (const float4*)spikes;
    const int base = (b * T_ + s * L_) * (D_ / 4) + dg;
    float4 e = ((const float4*)start_state)[(b * SEG_ + s) * (D_ / 4) + dg];
#pragma unroll 8
    for (int k = 0; k < L_; ++k) {
        float4 x = sp4[base + k * (D_ / 4)];
        e.x = DECAYF * e.x + OMDF * x.x;
        e.y = DECAYF * e.y + OMDF * x.y;
        e.z = DECAYF * e.z + OMDF * x.z;
        e.w = DECAYF * e.w + OMDF * x.w;
        ((int*)a_f8)[base + k * (D_ / 4)] =
            pk_fp8x4(8.f*e.x, 8.f*e.y, 8.f*e.z, 8.f*e.w);
    }
}

// ---------------------------------------------------------------------------
// K2: MX-fp8 MFMA GEMM, 32x32x64, async double-buffered pipeline.
// R7 post-mortem: reg-prefetch put the load vmcnt wait + ds_write phase ON
// the critical path (73.6 us, MfmaUtil 18%). Here: async global_load_lds
// (no VGPR staging) issues tile k+1's loads into buf 1-p at the TOP of the
// iter; frag reads + MFMAs of tile k from buf p run while those loads fly;
// the single __syncthreads per iter (vmcnt(0)+lgkmcnt(0)+s_barrier) drains
// loads that had the whole compute phase to land. Double buffer removes
// R6's pre-staging WAR barrier (2 barriers/iter -> 1).
// LDS layout per tile: 512 16B-chunks, chunk I at byte I*16 holds row I>>2,
// logical k-chunk (I&3)^((row>>1)&3) (XOR swizzle, conflict-free staging
// and frag reads). global_load_lds dest = wave-uniform base + lane*16.
// NOTE: plain __launch_bounds__(256). R5's (256,3) floor spilled the
// accumulators to scratch (WRITE_SIZE 557 MB). Never floor-cap this kernel.
__global__ __launch_bounds__(256)
void k2_mfma_flags(const unsigned char* __restrict__ A,   // a_f8 [R_ x D_]
                   const unsigned char* __restrict__ Bw,  // w_f8 [F_ x D_]
                   unsigned int* __restrict__ flags) {
    __shared__ __align__(16) unsigned char lA[2][128 * 64];
    __shared__ __align__(16) unsigned char lB[2][128 * 64];
    const int tid = threadIdx.x;
    const int w = tid >> 6;
    const int lane = tid & 63;
    const int m0 = blockIdx.y * 128;
    const int n0 = blockIdx.x * 128;
    const int wm = w >> 1, wn = w & 1;
    const int col = lane & 31;          // m (A) / n (B) within 32-tile
    const int kg  = lane >> 5;          // k-half: 0 or 1

    // Staging geometry: round r in {0,1}: chunk index I = r*256 + w*64 + lane.
    // Source: row = I>>2, swizzled k-chunk lc = (I&3)^((row>>1)&3).
    // Dest: wave-uniform base (r*256 + w*64)*16, HW adds lane*16.
    const int I0 = w * 64 + lane;
    const int I1 = 256 + w * 64 + lane;
    const int row0 = I0 >> 2, lc0 = (I0 & 3) ^ ((row0 >> 1) & 3);
    const int row1 = I1 >> 2, lc1 = (I1 & 3) ^ ((row1 >> 1) & 3);
    const size_t sA0 = (size_t)(m0 + row0) * D_ + lc0 * 16;
    const size_t sA1 = (size_t)(m0 + row1) * D_ + lc1 * 16;
    const size_t sB0 = (size_t)(n0 + row0) * D_ + lc0 * 16;
    const size_t sB1 = (size_t)(n0 + row1) * D_ + lc1 * 16;
    const int dst0 = (w * 64) * 16;           // wave-uniform LDS dest bases
    const int dst1 = (256 + w * 64) * 16;

    // Loop-invariant frag-read offsets (within one buffer):
    int offA[2][2], offB[2][2];
#pragma unroll
    for (int i = 0; i < 2; ++i) {
        const int ra = wm * 64 + i * 32 + col;
        const int swa = (ra >> 1) & 3;
        offA[i][0] = ra * 64 + ((2 * kg    ) ^ swa) * 16;
        offA[i][1] = ra * 64 + ((2 * kg + 1) ^ swa) * 16;
        const int rb = wn * 64 + i * 32 + col;
        const int swb = (rb >> 1) & 3;
        offB[i][0] = rb * 64 + ((2 * kg    ) ^ swb) * 16;
        offB[i][1] = rb * 64 + ((2 * kg + 1) ^ swb) * 16;
    }

    f32x16 acc[2][2] = {};

#define K2_STAGE(BUF, KOFF)                                                 \
    {                                                                       \
        gload_lds16(A  + sA0 + (size_t)(KOFF), &lA[BUF][dst0]);             \
        gload_lds16(A  + sA1 + (size_t)(KOFF), &lA[BUF][dst1]);             \
        gload_lds16(Bw + sB0 + (size_t)(KOFF), &lB[BUF][dst0]);             \
        gload_lds16(Bw + sB1 + (size_t)(KOFF), &lB[BUF][dst1]);             \
    }

#define K2_COMPUTE(PBUF)                                                    \
    {                                                                       \
        i32x8 af[2], bfr[2];                                                \
        _Pragma("unroll")                                                   \
        for (int i = 0; i < 2; ++i) {                                       \
            i32x4 a0 = *(const i32x4*)&lA[PBUF][offA[i][0]];                \
            i32x4 a1 = *(const i32x4*)&lA[PBUF][offA[i][1]];                \
            af[i] = (i32x8){a0.x, a0.y, a0.z, a0.w, a1.x, a1.y, a1.z, a1.w};\
            i32x4 b0 = *(const i32x4*)&lB[PBUF][offB[i][0]];                \
            i32x4 b1 = *(const i32x4*)&lB[PBUF][offB[i][1]];                \
            bfr[i] = (i32x8){b0.x, b0.y, b0.z, b0.w, b1.x, b1.y, b1.z, b1.w};\
        }                                                                   \
        _Pragma("unroll")                                                   \
        for (int i = 0; i < 2; ++i)                                         \
            _Pragma("unroll")                                               \
            for (int j = 0; j < 2; ++j)                                     \
                acc[i][j] = __builtin_amdgcn_mfma_scale_f32_32x32x64_f8f6f4(\
                    af[i], bfr[j], acc[i][j], 0, 0, 0, 124, 0, 124);        \
    }

    // Prologue: stage tile k=0 into buffer 0.
    K2_STAGE(0, 0);
    __syncthreads();

    // 16 K-steps of 64, unrolled x2 so buffer parity is compile-time.
    // Iter k: issue async loads for tile k+64 into buf 1-p (WAR-safe: that
    // buffer's readers finished before the previous barrier), compute tile k
    // from buf p, then one __syncthreads (drains vmcnt -> next tile ready).
    // Final stage wraps to k=0 (unused) — uniform code, no branch.
#pragma unroll
    for (int k0 = 0; k0 < D_; k0 += 128) {
        K2_STAGE(1, k0 + 64);
        K2_COMPUTE(0);
        __syncthreads();
        K2_STAGE(0, (k0 + 128) & (D_ - 1));
        K2_COMPUTE(1);
        __syncthreads();
    }
#undef K2_STAGE
#undef K2_COMPUTE

    // Epilogue: per-row spike flags. 32x32 C/D layout (m74/m101-verified):
    // col = lane&31, row = (reg&3) + 8*(reg>>2) + 4*(lane>>5).
#pragma unroll
    for (int i = 0; i < 2; ++i) {
#pragma unroll
        for (int reg = 0; reg < 16; ++reg) {
            float mx = fmaxf(acc[i][0][reg], acc[i][1][reg]);
            if (mx > FLAG_THRESH) {
                const int rr = (reg & 3) + 8 * (reg >> 2) + 4 * kg;
                atomicOr(&flags[m0 + wm * 64 + i * 32 + rr], 1u);
            }
        }
    }
}

// ---------------------------------------------------------------------------
// K4: one block per (b,t) row. Unflagged rows (the overwhelmingly common
// case) write zeros. Flagged rows take the exact fp32 slow path, rebuilding
// the EMA row from start_state + <=32 spike rows.
__global__ __launch_bounds__(256)
void k4_output(const float* __restrict__ spikes,
               const float* __restrict__ start_state,
               const float* __restrict__ W1,
               const float* __restrict__ Wr,
               const float* __restrict__ W2,
               const unsigned int* __restrict__ flags,
               float* __restrict__ out) {
    const int row = blockIdx.x;          // 0..R_-1
    const int tid = threadIdx.x;
    float4 o = {0.f, 0.f, 0.f, 0.f};

    if (flags[row] == 0u) {              // wave-uniform branch (per block)
        *(float4*)&out[(size_t)row * D_ + tid * 4] = o;
        return;
    }

    __shared__ float se[D_];
    __shared__ float sp[D_];
    __shared__ float red[256];
    __shared__ int nspk;
    __shared__ int spk_list[256];

    const int b = row / T_;
    const int t = row % T_;
    const int seg = t / L_;
    const int off = t % L_;
    const int segbase = (b * T_ + seg * L_) * D_;

    for (int i = tid; i < D_; i += 256) {
        float e = start_state[(b * SEG_ + seg) * D_ + i];
        for (int j = 0; j <= off; ++j)
            e = DECAYF * e + OMDF * spikes[segbase + j * D_ + i];
        se[i] = e;
        sp[i] = spikes[(size_t)row * D_ + i];
    }
    if (tid == 0) nspk = 0;
    __syncthreads();

    for (int f0 = 0; f0 < F_; f0 += 256) {
        int f = f0 + tid;
        float mix = 0.f;
        for (int k = 0; k < D_; ++k) mix += se[k] * W1[(size_t)f * D_ + k];
        if (mix > 0.5f) {
            int idx = atomicAdd(&nspk, 1);
            spk_list[idx] = f;
        }
        __syncthreads();
        int n = nspk;
        for (int i = 0; i < n; ++i) {
            int fs = spk_list[i];
            float part = 0.f;
#pragma unroll
            for (int k = 0; k < 4; ++k)
                part += sp[tid * 4 + k] * Wr[(size_t)fs * D_ + tid * 4 + k];
            red[tid] = part;
            __syncthreads();
            for (int sft = 128; sft > 0; sft >>= 1) {
                if (tid < sft) red[tid] += red[tid + sft];
                __syncthreads();
            }
            float r = 1.f / (1.f + expf(-red[0]));
            __syncthreads();
            o.x += r * W2[(size_t)(tid * 4 + 0) * F_ + fs];
            o.y += r * W2[(size_t)(tid * 4 + 1) * F_ + fs];
            o.z += r * W2[(size_t)(tid * 4 + 2) * F_ + fs];
            o.w += r * W2[(size_t)(tid * 4 + 3) * F_ + fs];
        }
        __syncthreads();
        if (tid == 0) nspk = 0;
        __syncthreads();
    }
    *(float4*)&out[(size_t)row * D_ + tid * 4] = o;
}

// ---------------------------------------------------------------------------
extern "C" void kernel_launch(void* const* d_in, const int* in_sizes, int n_in,
                              void* d_out, int out_size, void* d_ws, size_t ws_size,
                              hipStream_t stream) {
    const float* spikes = (const float*)d_in[0];   // [B,T,D]
    const float* W1     = (const float*)d_in[1];   // [F,D]
    const float* W2     = (const float*)d_in[2];   // [D,F]
    const float* Wr     = (const float*)d_in[3];   // [F,D]
    float* out = (float*)d_out;                    // [B,T,D]

    // workspace layout (~14.3 MB total)
    char* ws = (char*)d_ws;
    float* seg_sum      = (float*)ws;                                // 1 MB
    float* start_state  = seg_sum + (size_t)B_ * SEG_ * D_;          // 1 MB
    unsigned int* flags = (unsigned int*)(start_state + (size_t)B_ * SEG_ * D_); // 32 KB
    unsigned char* a_f8 = (unsigned char*)(flags + R_);              // 8 MB
    unsigned char* w_f8 = a_f8 + (size_t)R_ * D_;                    // 4 MB

    kA_prologue<<<KA_W1_BLOCKS + KA_SEG_BLOCKS + KA_FLAG_BLOCKS, 256, 0, stream>>>(
        spikes, W1, w_f8, seg_sum, flags);
    kB_seg_scan<<<(B_ * D_ * 64) / 256, 256, 0, stream>>>(seg_sum, start_state);
    kC_ema_fp8<<<(B_ * SEG_ * D_ / 4) / 256, 256, 0, stream>>>(spikes, start_state, a_f8);

    dim3 g2(F_ / 128, R_ / 128);
    k2_mfma_flags<<<g2, 256, 0, stream>>>(a_f8, w_f8, flags);

    k4_output<<<R_, 256, 0, stream>>>(spikes, start_state, W1, Wr, W2, flags, out);
}

// Round 9
// 186.794 us; speedup vs baseline: 1.1556x; 1.1556x over previous
//
#include <hip/hip_runtime.h>
#include <math.h>

// Problem constants (match reference)
#define B_    4
#define T_    2048
#define D_    1024
#define F_    4096
#define R_    (B_*T_)      // 8192 rows (b,t)
#define SEG_  64           // segments per time-chain
#define L_    (T_/SEG_)    // 32 steps per segment
#define DECAYF 0.9f
#define OMDF   0.1f        // 1 - decay
// Flag threshold below 0.5: the k4 fallback re-tests at exactly 0.5 in fp32,
// so flags only need NO FALSE NEGATIVES. fp8(x8-scaled) GEMM error is
// ~1e-3 RMS (6-sigma ~7e-3); margin 0.05 is ~7x worst plausible error.
#define FLAG_THRESH 0.45f

typedef __attribute__((ext_vector_type(4)))  int   i32x4;
typedef __attribute__((ext_vector_type(8)))  int   i32x8;
typedef __attribute__((ext_vector_type(16))) float f32x16;

// pack 4 floats into 4 fp8 e4m3 bytes (byte0 = first arg)
__device__ __forceinline__ int pk_fp8x4(float x, float y, float z, float w) {
    int p = 0;
    p = __builtin_amdgcn_cvt_pk_fp8_f32(x, y, p, false);  // bytes 0,1
    p = __builtin_amdgcn_cvt_pk_fp8_f32(z, w, p, true);   // bytes 2,3
    return p;
}

// ---------------------------------------------------------------------------
// PACKED OPERAND LAYOUT (R9): LDS was the k2 bottleneck (96 KB/CU-iter
// through the 128 B/cy pipe). Since we generate the fp8 arrays ourselves,
// emit them in MFMA-operand tile order so k2 needs NO LDS at all:
//   panel P = row>>5 (32 rows), k-chunk C = kbyte>>6 (64 B) -> 2 KB tile at
//   byte ((P*16 + C) * 2048). Within a tile, byte  h*1024 + l*16 + t  holds
//   element [row = P*32 + (l&31)][k = C*64 + (l>>5)*32 + h*16 + t].
// A wave's 32x32x64 fragment load = two 1 KB contiguous global_load_dwordx4
// (lane l at l*16, halves at +0/+1024) — perfectly coalesced, straight to
// VGPRs, zero LDS, zero barriers.
__device__ __forceinline__ size_t pk_off(int row, int d) {
    // byte offset of element [row][d] in the packed layout
    return ((size_t)((row >> 5) * 16 + (d >> 6)) * 2048)
         + ((d >> 4) & 1) * 1024
         + ((row & 31) + ((d >> 5) & 1) * 32) * 16
         + (d & 15);
}

// ---------------------------------------------------------------------------
// KA: fused prologue. Grid-partitioned roles:
//   blocks [0, 4096):       W1 fp32 -> fp8 e4m3 x8, packed operand layout
//   blocks [4096, 4352):    per-segment EMA end-state (seg_sum)
//   blocks [4352, 4384):    zero the 8192 per-row spike flags
#define KA_W1_BLOCKS  4096
#define KA_SEG_BLOCKS 256
#define KA_FLAG_BLOCKS 32

__global__ __launch_bounds__(256)
void kA_prologue(const float* __restrict__ spikes,
                 const float* __restrict__ W1,
                 unsigned char* __restrict__ w_f8,
                 float* __restrict__ seg_sum,
                 unsigned int* __restrict__ flags) {
    const int bid = blockIdx.x;
    const int tid = threadIdx.x;
    if (bid < KA_W1_BLOCKS) {
        int i = bid * 256 + tid;                  // float4 index over W1 [F x D]
        float4 v = ((const float4*)W1)[i];
        int f  = i >> 8;                          // D/4 = 256 groups per row
        int d0 = (i & 255) * 4;
        *(int*)(w_f8 + pk_off(f, d0)) = pk_fp8x4(8.f*v.x, 8.f*v.y, 8.f*v.z, 8.f*v.w);
    } else if (bid < KA_W1_BLOCKS + KA_SEG_BLOCKS) {
        int t = (bid - KA_W1_BLOCKS) * 256 + tid; // B_*SEG_*D_/4 threads
        int dg = t & (D_ / 4 - 1);
        int s = (t >> 8) & (SEG_ - 1);
        int b = t >> 14;
        const float4* sp4 = (const float4*)spikes;
        const int base = (b * T_ + s * L_) * (D_ / 4) + dg;
        float4 e = {0.f, 0.f, 0.f, 0.f};
#pragma unroll 8
        for (int k = 0; k < L_; ++k) {
            float4 x = sp4[base + k * (D_ / 4)];
            e.x = DECAYF * e.x + OMDF * x.x;
            e.y = DECAYF * e.y + OMDF * x.y;
            e.z = DECAYF * e.z + OMDF * x.z;
            e.w = DECAYF * e.w + OMDF * x.w;
        }
        ((float4*)seg_sum)[(b * SEG_ + s) * (D_ / 4) + dg] = e;
    } else {
        int i = (bid - KA_W1_BLOCKS - KA_SEG_BLOCKS) * 256 + tid;
        if (i < R_) flags[i] = 0u;
    }
}

// ---------------------------------------------------------------------------
// KB: weighted Kogge-Stone scan over the 64 segments of each (b,d) chain,
// one chain per 64-lane wave (lane = segment). start_state[s] = scan[s-1].
__global__ __launch_bounds__(256)
void kB_seg_scan(const float* __restrict__ seg_sum,
                 float* __restrict__ start_state) {
    int g = blockIdx.x * 256 + threadIdx.x;   // B_*D_*64 threads
    int s = g & 63;                           // segment = lane
    int c = g >> 6;                           // chain id: 0..B_*D_-1
    int d = c & (D_ - 1);
    int b = c >> 10;
    int idx = (b * SEG_ + s) * D_ + d;
    float v = seg_sum[idx];
    float wp = 0.0343368382f;                 // 0.9^32 (per-segment decay)
#pragma unroll
    for (int off = 1; off < SEG_; off <<= 1) {
        float u = __shfl_up(v, off, 64);
        if (s >= off) v += wp * u;
        wp *= wp;                             // w^1, w^2, w^4, ...
    }
    float pv = __shfl_up(v, 1, 64);
    start_state[idx] = (s == 0) ? 0.f : pv;
}

// ---------------------------------------------------------------------------
// KC: recompute segment-local EMA seeded with start_state; emit fp8 (x8)
// into the packed operand layout. For thread (b,s,dg): global row
// r = b*T + s*32 + k, so P = b*64+s and r&31 = k — the tile indices (P, C,
// h, t, l-high) are loop-invariant; only l's low 5 bits advance with k.
__global__ __launch_bounds__(256)
void kC_ema_fp8(const float* __restrict__ spikes,
                const float* __restrict__ start_state,
                unsigned char* __restrict__ a_f8) {
    int t = blockIdx.x * 256 + threadIdx.x;            // B_*SEG_*D_/4 threads
    int dg = t & (D_ / 4 - 1);
    int s = (t >> 8) & (SEG_ - 1);
    int b = t >> 14;
    const float4* sp4 = (const float4*)spikes;
    const int base = (b * T_ + s * L_) * (D_ / 4) + dg;
    const int d0 = dg * 4;
    unsigned char* dst = a_f8 + pk_off(b * T_ + s * L_, d0);   // k=0 element
    float4 e = ((const float4*)start_state)[(b * SEG_ + s) * (D_ / 4) + dg];
#pragma unroll 8
    for (int k = 0; k < L_; ++k) {
        float4 x = sp4[base + k * (D_ / 4)];
        e.x = DECAYF * e.x + OMDF * x.x;
        e.y = DECAYF * e.y + OMDF * x.y;
        e.z = DECAYF * e.z + OMDF * x.z;
        e.w = DECAYF * e.w + OMDF * x.w;
        *(int*)(dst + k * 16) = pk_fp8x4(8.f*e.x, 8.f*e.y, 8.f*e.z, 8.f*e.w);
    }
}

// ---------------------------------------------------------------------------
// K2: MX-fp8 32x32x64 streaming GEMM, NO LDS, NO BARRIERS (R9).
// Operands are pre-packed (see pk_off): each fragment is two coalesced 1 KB
// global_load_dwordx4 straight into VGPRs. 128x128 block tile, 4 waves 2x2,
// each wave a 2x2 grid of 32x32x64 MFMAs; 2-stage register prefetch. With
// no barrier anywhere, the compiler's vmcnt waits are fine-grained (never a
// full drain) and loads pipeline across iterations and across waves.
// Uniform e8m0 scales = 2^-3 (values stored x8) keep acc exact in scale.
// NOTE: plain __launch_bounds__(256). R5's (256,3) floor spilled the
// accumulators to scratch (WRITE_SIZE 557 MB). Never floor-cap this kernel.
__global__ __launch_bounds__(256)
void k2_mfma_flags(const unsigned char* __restrict__ Ap,  // packed a_f8
                   const unsigned char* __restrict__ Bp,  // packed w_f8
                   unsigned int* __restrict__ flags) {
    const int tid = threadIdx.x;
    const int w = tid >> 6;
    const int lane = tid & 63;
    const int m0 = blockIdx.y * 128;
    const int n0 = blockIdx.x * 128;
    const int wm = w >> 1, wn = w & 1;
    const int kg = lane >> 5;

    // Per-lane stream base pointers: 4 operand streams (2 A tiles, 2 B tiles).
    // Panel P's 16 k-tiles are contiguous (32 KB); iter C reads at +C*2048.
    const unsigned char* a0 = Ap + ((size_t)((m0 >> 5) + wm * 2 + 0) * 16) * 2048 + lane * 16;
    const unsigned char* a1 = Ap + ((size_t)((m0 >> 5) + wm * 2 + 1) * 16) * 2048 + lane * 16;
    const unsigned char* b0 = Bp + ((size_t)((n0 >> 5) + wn * 2 + 0) * 16) * 2048 + lane * 16;
    const unsigned char* b1 = Bp + ((size_t)((n0 >> 5) + wn * 2 + 1) * 16) * 2048 + lane * 16;

    f32x16 acc[2][2] = {};

#define LDFRAG(p, C)                                                        \
    ({ i32x4 lo_ = *(const i32x4*)((p) + (size_t)(C) * 2048);               \
       i32x4 hi_ = *(const i32x4*)((p) + (size_t)(C) * 2048 + 1024);        \
       (i32x8){lo_.x, lo_.y, lo_.z, lo_.w, hi_.x, hi_.y, hi_.z, hi_.w}; })

#define MFMA4(AF0, AF1, BF0, BF1)                                           \
    {                                                                       \
        acc[0][0] = __builtin_amdgcn_mfma_scale_f32_32x32x64_f8f6f4(        \
            AF0, BF0, acc[0][0], 0, 0, 0, 124, 0, 124);                     \
        acc[0][1] = __builtin_amdgcn_mfma_scale_f32_32x32x64_f8f6f4(        \
            AF0, BF1, acc[0][1], 0, 0, 0, 124, 0, 124);                     \
        acc[1][0] = __builtin_amdgcn_mfma_scale_f32_32x32x64_f8f6f4(        \
            AF1, BF0, acc[1][0], 0, 0, 0, 124, 0, 124);                     \
        acc[1][1] = __builtin_amdgcn_mfma_scale_f32_32x32x64_f8f6f4(        \
            AF1, BF1, acc[1][1], 0, 0, 0, 124, 0, 124);                     \
    }

    // 2-stage register prefetch over 16 k-chunks, unrolled x2 (two frag
    // sets, no register copies). Final prefetch wraps to C=0 (harmless).
    i32x8 A0a = LDFRAG(a0, 0), A1a = LDFRAG(a1, 0);
    i32x8 B0a = LDFRAG(b0, 0), B1a = LDFRAG(b1, 0);
#pragma unroll
    for (int C = 0; C < 16; C += 2) {
        i32x8 A0b = LDFRAG(a0, C + 1), A1b = LDFRAG(a1, C + 1);
        i32x8 B0b = LDFRAG(b0, C + 1), B1b = LDFRAG(b1, C + 1);
        MFMA4(A0a, A1a, B0a, B1a);
        const int C2 = (C + 2) & 15;
        A0a = LDFRAG(a0, C2); A1a = LDFRAG(a1, C2);
        B0a = LDFRAG(b0, C2); B1a = LDFRAG(b1, C2);
        MFMA4(A0b, A1b, B0b, B1b);
    }
#undef LDFRAG
#undef MFMA4

    // Epilogue: per-row spike flags. 32x32 C/D layout (m74/m101-verified):
    // col = lane&31, row = (reg&3) + 8*(reg>>2) + 4*(lane>>5).
#pragma unroll
    for (int i = 0; i < 2; ++i) {
#pragma unroll
        for (int reg = 0; reg < 16; ++reg) {
            float mx = fmaxf(acc[i][0][reg], acc[i][1][reg]);
            if (mx > FLAG_THRESH) {
                const int rr = (reg & 3) + 8 * (reg >> 2) + 4 * kg;
                atomicOr(&flags[m0 + wm * 64 + i * 32 + rr], 1u);
            }
        }
    }
}

// ---------------------------------------------------------------------------
// K4: one block per (b,t) row. Unflagged rows (the overwhelmingly common
// case) write zeros. Flagged rows take the exact fp32 slow path, rebuilding
// the EMA row from start_state + <=32 spike rows.
__global__ __launch_bounds__(256)
void k4_output(const float* __restrict__ spikes,
               const float* __restrict__ start_state,
               const float* __restrict__ W1,
               const float* __restrict__ Wr,
               const float* __restrict__ W2,
               const unsigned int* __restrict__ flags,
               float* __restrict__ out) {
    const int row = blockIdx.x;          // 0..R_-1
    const int tid = threadIdx.x;
    float4 o = {0.f, 0.f, 0.f, 0.f};

    if (flags[row] == 0u) {              // wave-uniform branch (per block)
        *(float4*)&out[(size_t)row * D_ + tid * 4] = o;
        return;
    }

    __shared__ float se[D_];
    __shared__ float sp[D_];
    __shared__ float red[256];
    __shared__ int nspk;
    __shared__ int spk_list[256];

    const int b = row / T_;
    const int t = row % T_;
    const int seg = t / L_;
    const int off = t % L_;
    const int segbase = (b * T_ + seg * L_) * D_;

    for (int i = tid; i < D_; i += 256) {
        float e = start_state[(b * SEG_ + seg) * D_ + i];
        for (int j = 0; j <= off; ++j)
            e = DECAYF * e + OMDF * spikes[segbase + j * D_ + i];
        se[i] = e;
        sp[i] = spikes[(size_t)row * D_ + i];
    }
    if (tid == 0) nspk = 0;
    __syncthreads();

    for (int f0 = 0; f0 < F_; f0 += 256) {
        int f = f0 + tid;
        float mix = 0.f;
        for (int k = 0; k < D_; ++k) mix += se[k] * W1[(size_t)f * D_ + k];
        if (mix > 0.5f) {
            int idx = atomicAdd(&nspk, 1);
            spk_list[idx] = f;
        }
        __syncthreads();
        int n = nspk;
        for (int i = 0; i < n; ++i) {
            int fs = spk_list[i];
            float part = 0.f;
#pragma unroll
            for (int k = 0; k < 4; ++k)
                part += sp[tid * 4 + k] * Wr[(size_t)fs * D_ + tid * 4 + k];
            red[tid] = part;
            __syncthreads();
            for (int sft = 128; sft > 0; sft >>= 1) {
                if (tid < sft) red[tid] += red[tid + sft];
                __syncthreads();
            }
            float r = 1.f / (1.f + expf(-red[0]));
            __syncthreads();
            o.x += r * W2[(size_t)(tid * 4 + 0) * F_ + fs];
            o.y += r * W2[(size_t)(tid * 4 + 1) * F_ + fs];
            o.z += r * W2[(size_t)(tid * 4 + 2) * F_ + fs];
            o.w += r * W2[(size_t)(tid * 4 + 3) * F_ + fs];
        }
        __syncthreads();
        if (tid == 0) nspk = 0;
        __syncthreads();
    }
    *(float4*)&out[(size_t)row * D_ + tid * 4] = o;
}

// ---------------------------------------------------------------------------
extern "C" void kernel_launch(void* const* d_in, const int* in_sizes, int n_in,
                              void* d_out, int out_size, void* d_ws, size_t ws_size,
                              hipStream_t stream) {
    const float* spikes = (const float*)d_in[0];   // [B,T,D]
    const float* W1     = (const float*)d_in[1];   // [F,D]
    const float* W2     = (const float*)d_in[2];   // [D,F]
    const float* Wr     = (const float*)d_in[3];   // [F,D]
    float* out = (float*)d_out;                    // [B,T,D]

    // workspace layout (~14.3 MB total)
    char* ws = (char*)d_ws;
    float* seg_sum      = (float*)ws;                                // 1 MB
    float* start_state  = seg_sum + (size_t)B_ * SEG_ * D_;          // 1 MB
    unsigned int* flags = (unsigned int*)(start_state + (size_t)B_ * SEG_ * D_); // 32 KB
    unsigned char* a_f8 = (unsigned char*)(flags + R_);              // 8 MB, packed
    unsigned char* w_f8 = a_f8 + (size_t)R_ * D_;                    // 4 MB, packed

    kA_prologue<<<KA_W1_BLOCKS + KA_SEG_BLOCKS + KA_FLAG_BLOCKS, 256, 0, stream>>>(
        spikes, W1, w_f8, seg_sum, flags);
    kB_seg_scan<<<(B_ * D_ * 64) / 256, 256, 0, stream>>>(seg_sum, start_state);
    kC_ema_fp8<<<(B_ * SEG_ * D_ / 4) / 256, 256, 0, stream>>>(spikes, start_state, a_f8);

    dim3 g2(F_ / 128, R_ / 128);
    k2_mfma_flags<<<g2, 256, 0, stream>>>(a_f8, w_f8, flags);

    k4_output<<<R_, 256, 0, stream>>>(spikes, start_state, W1, Wr, W2, flags, out);
}